// Round 7
// baseline (186.296 us; speedup 1.0000x reference)
//
#include <hip/hip_runtime.h>
#include <hip/hip_bf16.h>
#include <hip/hip_cooperative_groups.h>

namespace cg = cooperative_groups;

#define DDIM 256
#define NROWS 8192

typedef __attribute__((ext_vector_type(8))) __bf16 bf16x8;
typedef __attribute__((ext_vector_type(4))) float floatx4;

// async global->LDS, 16B per lane. LDS dest is wave-uniform base + lane*16.
__device__ __forceinline__ void async16(const void* g, void* l) {
    __builtin_amdgcn_global_load_lds(
        (const __attribute__((address_space(1))) unsigned int*)g,
        (__attribute__((address_space(3))) unsigned int*)l,
        16, 0, 0);
}

// raw v_exp_f32: returns 2^x (one transcendental)
__device__ __forceinline__ float fexp2(float x) {
    float r; asm("v_exp_f32 %0, %1" : "=v"(r) : "v"(x)); return r;
}

// Stage 8 rows (4 KB) of a 64-row B tile per wave into LDS at l (4 async16).
// Linear layout with granule swizzle: stored granule g holds logical g^(r&7).
__device__ __forceinline__ void stage8(const unsigned short* __restrict__ g,
                                       unsigned short* l, int wv, int lane)
{
    const int lrow = lane >> 5;       // 0..1
    const int gcol = lane & 31;       // granule 0..31
    const int r0 = wv * 8;
    #pragma unroll
    for (int j = 0; j < 4; ++j) {
        const int rb = r0 + j * 2;
        const int r  = rb + lrow;
        const int gg = gcol ^ (r & 7);
        async16(g + (size_t)r * DDIM + gg * 8, l + (size_t)rb * DDIM);
    }
}

// ONE fused cooperative kernel: normalize -> grid.sync -> persistent-A GEMM
// + exp-rowsum -> ticket finalize. Eliminates the second dispatch and the
// ~60 us constant inter-dispatch overhead seen in every prior round.
// GEMM phase is R6's structure verbatim (best measured: 83.7 us):
//   256 blocks x 512 thr (8 waves), 1 block/CU. Block = 256 rows x 1024
//   cols; wave = 32 rows (afr[2][8]=64 regs direct from global). B quad-
//   buffered 4 x 32 KB (128 KB LDS), 16 tiles of 64 cols. Slot i: counted
//   vmcnt(8) -> barrier -> stage tile i+3 into freed buffer -> compute with
//   one-phase-ahead ds_read ping-pong + setprio'd 16-MFMA clusters.
// grid.sync provides the cross-XCD release/acquire for Un/Pn/possim and
// drains vmem, so the GEMM's counted-vmcnt bookkeeping starts from zero.
__global__ __launch_bounds__(512, 2) void fused_loss(
    const float* __restrict__ U, const float* __restrict__ P,
    unsigned short* __restrict__ Un, unsigned short* __restrict__ Pn,
    float* __restrict__ rowsum, float* __restrict__ possim,
    int* __restrict__ counter, float* __restrict__ out)
{
    __shared__ __align__(16) unsigned short lds[65536];   // 128 KB: 4 x 32 KB B bufs
    __shared__ float ws8[8];
    __shared__ int ticket_s;

    const int tid  = threadIdx.x;
    const int lane = tid & 63;
    const int wv   = tid >> 6;          // 0..7
    const int m = lane & 15;
    const int q = lane >> 4;

    // ---- Phase 0: L2-normalize this block's 32-row slice of U and P ----
    if (blockIdx.x == 0 && tid == 0) counter[0] = 0;
    {
        const int r0 = blockIdx.x * 32 + wv * 4;    // 256 blk x 32 = 8192 rows
        #pragma unroll
        for (int rr = 0; rr < 4; ++rr) {
            const int row = r0 + rr;
            const size_t base = (size_t)row * DDIM + lane * 4;
            const float4 u4 = *(const float4*)(U + base);
            const float4 p4 = *(const float4*)(P + base);
            float su = u4.x*u4.x + u4.y*u4.y + u4.z*u4.z + u4.w*u4.w;
            float sp = p4.x*p4.x + p4.y*p4.y + p4.z*p4.z + p4.w*p4.w;
            float up = u4.x*p4.x + u4.y*p4.y + u4.z*p4.z + u4.w*p4.w;
            #pragma unroll
            for (int d = 1; d < 64; d <<= 1) {
                su += __shfl_xor(su, d);
                sp += __shfl_xor(sp, d);
                up += __shfl_xor(up, d);
            }
            const float iu = rsqrtf(fmaxf(su, 1e-24f));
            const float ip = rsqrtf(fmaxf(sp, 1e-24f));
            if (lane == 0) possim[row] = up * iu * ip;
            union { ushort4 s4; __hip_bfloat16 h[4]; } cu, cp;
            cu.h[0] = __float2bfloat16(u4.x * iu);
            cu.h[1] = __float2bfloat16(u4.y * iu);
            cu.h[2] = __float2bfloat16(u4.z * iu);
            cu.h[3] = __float2bfloat16(u4.w * iu);
            cp.h[0] = __float2bfloat16(p4.x * ip);
            cp.h[1] = __float2bfloat16(p4.y * ip);
            cp.h[2] = __float2bfloat16(p4.z * ip);
            cp.h[3] = __float2bfloat16(p4.w * ip);
            *(ushort4*)(Un + base) = cu.s4;
            *(ushort4*)(Pn + base) = cp.s4;
        }
        if (tid < 32) rowsum[blockIdx.x * 32 + tid] = 0.0f;
    }

    cg::this_grid().sync();   // Un/Pn/possim/rowsum visible device-wide

    // ---- Phase 1: GEMM + exp-rowsum (R6 verbatim) ----
    const int stripe = blockIdx.x >> 3;   // 0..31  (256-row stripes)
    const int oct    = blockIdx.x & 7;    // 0..7   (1024-col groups == XCD)

    // A-frags straight from global (one-time, L2/L3-hot)
    const unsigned short* Arow = Un + (size_t)(stripe * 256 + wv * 32 + m) * DDIM;
    bf16x8 afr[2][8];
    #pragma unroll
    for (int t = 0; t < 2; ++t)
        #pragma unroll
        for (int ks = 0; ks < 8; ++ks)
            afr[t][ks] = *(const bf16x8*)(Arow + t * 16 * DDIM + (ks * 4 + q) * 8);

    // B-frag addressing: addr = Bp + bb[par] + n*8192 + P*128
    // reproduces row*512 + ((ks*4+q)^(m&7))*16 for row = n*16+m, ks = 2P+par.
    const int c10 = m & 3, c2 = (m >> 2) & 1;
    const unsigned bb0 = (unsigned)(m * 512 + ((q ^ c10) << 4) + ((0 ^ c2) << 6));
    const unsigned bb1 = (unsigned)(m * 512 + ((q ^ c10) << 4) + ((1 ^ c2) << 6));

    const unsigned short* Bglob = Pn + (size_t)(oct * 1024) * DDIM;
    float rowpart[2][4] = {{0.f, 0.f, 0.f, 0.f}, {0.f, 0.f, 0.f, 0.f}};

    // Prologue: stage tiles 0..2, single full drain (also covers A-loads)
    stage8(Bglob,              lds,         wv, lane);
    stage8(Bglob + 64 * DDIM,  lds + 16384, wv, lane);
    stage8(Bglob + 128 * DDIM, lds + 32768, wv, lane);
    asm volatile("s_waitcnt vmcnt(0)" ::: "memory");
    __builtin_amdgcn_s_barrier();

#define LOADPH(BP, P, F)                                                     \
    do {                                                                     \
        F[0] = *(const bf16x8*)((BP) + bb0 + 0 * 8192 + (P) * 128);          \
        F[1] = *(const bf16x8*)((BP) + bb0 + 1 * 8192 + (P) * 128);          \
        F[2] = *(const bf16x8*)((BP) + bb0 + 2 * 8192 + (P) * 128);          \
        F[3] = *(const bf16x8*)((BP) + bb0 + 3 * 8192 + (P) * 128);          \
        F[4] = *(const bf16x8*)((BP) + bb1 + 0 * 8192 + (P) * 128);          \
        F[5] = *(const bf16x8*)((BP) + bb1 + 1 * 8192 + (P) * 128);          \
        F[6] = *(const bf16x8*)((BP) + bb1 + 2 * 8192 + (P) * 128);          \
        F[7] = *(const bf16x8*)((BP) + bb1 + 3 * 8192 + (P) * 128);          \
    } while (0)

#define MMAPH(P, F)                                                          \
    do {                                                                     \
        __builtin_amdgcn_s_setprio(1);                                       \
        _Pragma("unroll")                                                    \
        for (int n = 0; n < 4; ++n) {                                        \
            acc[0][n] = __builtin_amdgcn_mfma_f32_16x16x32_bf16(             \
                afr[0][2 * (P)], F[n], acc[0][n], 0, 0, 0);                  \
            acc[1][n] = __builtin_amdgcn_mfma_f32_16x16x32_bf16(             \
                afr[1][2 * (P)], F[n], acc[1][n], 0, 0, 0);                  \
            acc[0][n] = __builtin_amdgcn_mfma_f32_16x16x32_bf16(             \
                afr[0][2 * (P) + 1], F[n + 4], acc[0][n], 0, 0, 0);          \
            acc[1][n] = __builtin_amdgcn_mfma_f32_16x16x32_bf16(             \
                afr[1][2 * (P) + 1], F[n + 4], acc[1][n], 0, 0, 0);          \
        }                                                                    \
        __builtin_amdgcn_s_setprio(0);                                       \
    } while (0)

    // Main loop: 16 col-tiles of 64, quad-buffered, depth-2/3
    for (int i = 0; i < 16; ++i) {
        if (i > 0) {
            if (i <= 13)      asm volatile("s_waitcnt vmcnt(8)" ::: "memory");
            else if (i == 14) asm volatile("s_waitcnt vmcnt(4)" ::: "memory");
            else              asm volatile("s_waitcnt vmcnt(0)" ::: "memory");
            __builtin_amdgcn_s_barrier();   // frees buf (i-1)&3 == (i+3)&3
        }
        if (i + 3 < 16)
            stage8(Bglob + (size_t)(i + 3) * 64 * DDIM,
                   lds + ((i + 3) & 3) * 16384, wv, lane);

        const char* Bp = (const char*)lds + (i & 3) * 32768;
        floatx4 acc[2][4];
        #pragma unroll
        for (int t = 0; t < 2; ++t)
            #pragma unroll
            for (int n = 0; n < 4; ++n)
                acc[t][n] = {0.0f, 0.0f, 0.0f, 0.0f};

        bf16x8 fA[8], fB[8];
        LOADPH(Bp, 0, fA);      // phase 0 frags
        LOADPH(Bp, 1, fB);      // phase 1 frags in flight over phase-0 MFMAs
        MMAPH(0, fA);
        LOADPH(Bp, 2, fA);
        MMAPH(1, fB);
        LOADPH(Bp, 3, fB);
        MMAPH(2, fA);
        MMAPH(3, fB);

        // exp(5*sim) = 2^(sim*5*log2 e); C/D: col = m, row = q*4+r (+t*16)
        #pragma unroll
        for (int t = 0; t < 2; ++t)
            #pragma unroll
            for (int n = 0; n < 4; ++n)
                #pragma unroll
                for (int r = 0; r < 4; ++r)
                    rowpart[t][r] += fexp2(acc[t][n][r] * 7.2134752044448169f);
    }
#undef LOADPH
#undef MMAPH

    // ---- Epilogue: reduce 16 column-lanes, one atomic per row per wave ----
    #pragma unroll
    for (int t = 0; t < 2; ++t) {
        #pragma unroll
        for (int r = 0; r < 4; ++r) {
            float s = rowpart[t][r];
            s += __shfl_xor(s, 1);
            s += __shfl_xor(s, 2);
            s += __shfl_xor(s, 4);
            s += __shfl_xor(s, 8);
            if (m == 0) {
                const int grow = stripe * 256 + wv * 32 + t * 16 + q * 4 + r;
                atomicAdd(&rowsum[grow], s);
            }
        }
    }

    // ---- Fused finalize: last block computes the loss ----
    __threadfence();
    __syncthreads();   // this block's atomics are visible
    if (tid == 0)
        ticket_s = __hip_atomic_fetch_add(counter, 1, __ATOMIC_ACQ_REL,
                                          __HIP_MEMORY_SCOPE_AGENT);
    __syncthreads();
    if (ticket_s == 255) {
        float part = 0.0f;
        for (int i = tid; i < NROWS; i += 512) {
            const float rs = __hip_atomic_load(&rowsum[i], __ATOMIC_RELAXED,
                                               __HIP_MEMORY_SCOPE_AGENT);
            part += __logf(rs) - 5.0f * possim[i];
        }
        #pragma unroll
        for (int d = 1; d < 64; d <<= 1) part += __shfl_xor(part, d);
        if (lane == 0) ws8[wv] = part;
        __syncthreads();
        if (tid == 0) {
            float tot = 0.0f;
            #pragma unroll
            for (int w = 0; w < 8; ++w) tot += ws8[w];
            out[0] = tot * (1.0f / (float)NROWS);
        }
    }
}

extern "C" void kernel_launch(void* const* d_in, const int* in_sizes, int n_in,
                              void* d_out, int out_size, void* d_ws, size_t ws_size,
                              hipStream_t stream) {
    const float* U = (const float*)d_in[0];
    const float* P = (const float*)d_in[1];
    float* out = (float*)d_out;
    char* ws = (char*)d_ws;
    // ws: Un bf16 (4 MB) | Pn bf16 (4 MB) | rowsum f32 (32 KB) | possim f32 (32 KB) | counter
    unsigned short* Un = (unsigned short*)ws;
    unsigned short* Pn = (unsigned short*)(ws + 4194304);
    float* rowsum = (float*)(ws + 8388608);
    float* possim = (float*)(ws + 8388608 + 32768);
    int* counter  = (int*)(ws + 8388608 + 65536);

    void* args[] = {(void*)&U, (void*)&P, (void*)&Un, (void*)&Pn,
                    (void*)&rowsum, (void*)&possim, (void*)&counter, (void*)&out};
    hipLaunchCooperativeKernel((const void*)fused_loss, dim3(256), dim3(512),
                               args, 0, stream);
}